// Round 6
// baseline (2741.099 us; speedup 1.0000x reference)
//
#include <hip/hip_runtime.h>

typedef unsigned short u16;
typedef unsigned int u32;
typedef __bf16 bf16x8 __attribute__((ext_vector_type(8)));
typedef float f32x4 __attribute__((ext_vector_type(4)));

#define LN_EPS 1e-5f
#define L2E 1.44269504f

__device__ __forceinline__ u16 f2bf(float f) {
    u32 u = __float_as_uint(f);
    u += 0x7fffu + ((u >> 16) & 1u);
    return (u16)(u >> 16);
}
__device__ __forceinline__ float bf2f(u32 v) {
    return __uint_as_float(v << 16);
}
__device__ __forceinline__ void unp8(uint4 u, float* v) {
    v[0] = bf2f(u.x & 0xffff); v[1] = bf2f(u.x >> 16);
    v[2] = bf2f(u.y & 0xffff); v[3] = bf2f(u.y >> 16);
    v[4] = bf2f(u.z & 0xffff); v[5] = bf2f(u.z >> 16);
    v[6] = bf2f(u.w & 0xffff); v[7] = bf2f(u.w >> 16);
}
__device__ __forceinline__ u32 pk2(float a, float b) {
    return (u32)f2bf(a) | ((u32)f2bf(b) << 16);
}

// async global->LDS, 16B per lane; lds base must be wave-uniform (HW: base + lane*16)
#define ASYNC_CP16(g, l)                                                      \
    __builtin_amdgcn_global_load_lds(                                         \
        (const __attribute__((address_space(1))) u32*)(g),                    \
        (__attribute__((address_space(3))) u32*)(l), 16, 0, 0)

// ---------------- one-shot prep: all weight transposes (f32->bf16) + bias concat ----
// jobs: [0,4096) wq/wk/wv/wo (32x32 grid each); [4096,8192) w1 (128x32);
//       [8192,12288) w2 (32x128); [12288,12300) qkvb concat.
__global__ __launch_bounds__(256) void k_prep(
    const float* __restrict__ wq, const float* __restrict__ wk,
    const float* __restrict__ wv, const float* __restrict__ wo,
    const float* __restrict__ w1, const float* __restrict__ w2,
    const float* __restrict__ bq, const float* __restrict__ bk,
    const float* __restrict__ bv, float* __restrict__ qkvb,
    u16* __restrict__ wqkvT, u16* __restrict__ woT,
    u16* __restrict__ w1T, u16* __restrict__ w2T)
{
    int b = blockIdx.x;
    if (b >= 12288) {
        int i = (b - 12288) * 256 + threadIdx.x;
        qkvb[i] = (i < 1024) ? bq[i] : (i < 2048 ? bk[i - 1024] : bv[i - 2048]);
        return;
    }
    const float* in; u16* out; int C; long ldo; int gx; int l;
    if (b < 4096) {
        int j = b >> 10; l = b & 1023;
        in = (j == 0) ? wq : (j == 1) ? wk : (j == 2) ? wv : wo;
        out = (j == 3) ? woT : wqkvT + (long)j * 1024 * 1024;
        C = 1024; ldo = 1024; gx = 32;
    } else if (b < 8192) {
        l = b - 4096; in = w1; out = w1T; C = 4096; ldo = 1024; gx = 128;
    } else {
        l = b - 8192; in = w2; out = w2T; C = 1024; ldo = 4096; gx = 32;
    }
    int bx = l % gx, by = l / gx;
    __shared__ float tile[32][33];
    int c0 = bx * 32, r0 = by * 32;
    int tx = threadIdx.x & 31, ty = threadIdx.x >> 5;
#pragma unroll
    for (int i = 0; i < 4; i++)
        tile[ty + 8 * i][tx] = in[(long)(r0 + ty + 8 * i) * C + c0 + tx];
    __syncthreads();
#pragma unroll
    for (int i = 0; i < 4; i++)
        out[(long)(c0 + ty + 8 * i) * ldo + r0 + tx] = f2bf(tile[tx][ty + 8 * i]);
}

// ---------------- embedding: xb = bf16(emb[id]*32 + pe) ----------------
__global__ __launch_bounds__(256) void k_embed(
    const int* __restrict__ ids, const float* __restrict__ emb,
    const float* __restrict__ pe, u16* __restrict__ xb)
{
    int row = blockIdx.x;          // b*512 + l
    int l = row & 511;
    long id = (long)ids[row];
    const float* e = emb + id * 1024;
    const float* p = pe + (long)l * 1024;
    u16* xbo = xb + (long)row * 1024;
    int d0 = threadIdx.x * 4;
    float4 ev = *(const float4*)&e[d0];
    float4 pv = *(const float4*)&p[d0];
    ushort4 o;
    o.x = f2bf(ev.x * 32.0f + pv.x);
    o.y = f2bf(ev.y * 32.0f + pv.y);
    o.z = f2bf(ev.z * 32.0f + pv.z);
    o.w = f2bf(ev.w * 32.0f + pv.w);
    *(ushort4*)&xbo[d0] = o;
}

// ---------------- bf16 MFMA GEMM, NT form: C[m][n] = alpha*sum_k A[m][k]*B[n][k] + bias ----
// A staged via global_load_lds (LDS 2 K-planes); B read DIRECTLY from global (L2) into
// VGPR frags — halves LDS pipe traffic and the per-barrier vmcnt drain.
// Grid: x = m-tile (fastest), y = n-tile -> consecutive blocks share one B panel (L2 reuse).
// If vTout != null (bf16 out): cols gn>=2048 are written transposed to vTout[gn-2048][gm] (ld 512).
template <int TM, int TN, bool OUT_BF16>
__global__ __launch_bounds__(256) void k_gemm_nt(
    const u16* __restrict__ A, long lda,
    const u16* __restrict__ B, long ldb,
    void* __restrict__ Cm, long ldc,
    int M, int N, int K,
    const float* __restrict__ bias, int biasMode, float alpha,
    u16* __restrict__ vTout)
{
    constexpr int FM = TM / 32;     // m-frags per wave
    constexpr int FN = TN / 32;     // n-frags per wave
    constexpr int CPA = TM / 64;    // A chunks per wave per K-plane
    __shared__ u16 As[2 * TM * 32];
    int m0 = blockIdx.x * TM, n0 = blockIdx.y * TN;
    int tid = threadIdx.x;
    int lane = tid & 63, wid = tid >> 6;
    int wr = wid >> 1, wc = wid & 1;
    int quad = lane >> 4, l16 = lane & 15;

    f32x4 acc[FM][FN];
#pragma unroll
    for (int i = 0; i < FM; i++)
#pragma unroll
        for (int j = 0; j < FN; j++) acc[i][j] = {0.f, 0.f, 0.f, 0.f};

    // A staging: chunk = 16 rows x 32 k (1KB); lane l -> row c*16 + l/4, k-seg (l%4)*8
    int seg = (lane & 3) * 8;
    const u16* pA[CPA]; u16* lA[2][CPA];
#pragma unroll
    for (int i = 0; i < CPA; i++) {
        int c = wid * CPA + i;
        int gm = min(m0 + c * 16 + (lane >> 2), M - 1);
        pA[i] = A + (long)gm * lda + seg;
        lA[0][i] = &As[c * 512];
        lA[1][i] = &As[TM * 32 + c * 512];
    }
    // B frag row pointers (per t): row n0 + wc*(TN/2) + t*16 + l16, k offset quad*8
    const u16* pBf[FN];
#pragma unroll
    for (int t = 0; t < FN; t++) {
        int gn = min(n0 + wc * (TN / 2) + t * 16 + l16, N - 1);
        pBf[t] = B + (long)gn * ldb + quad * 8;
    }

    for (int kb = 0; kb < K; kb += 64) {
        // B direct loads (global->VGPR, barrier-independent)
        bf16x8 bg[2][FN];
#pragma unroll
        for (int kh = 0; kh < 2; kh++)
#pragma unroll
            for (int t = 0; t < FN; t++)
                bg[kh][t] = *(const bf16x8*)(pBf[t] + kb + kh * 32);
        // A staging
#pragma unroll
        for (int kh = 0; kh < 2; kh++)
#pragma unroll
            for (int i = 0; i < CPA; i++) ASYNC_CP16(pA[i] + kb + kh * 32, lA[kh][i]);
        __syncthreads();   // drains A cp16s (and bg loads)
        bf16x8 af[2][FM];
#pragma unroll
        for (int kh = 0; kh < 2; kh++)
#pragma unroll
            for (int t = 0; t < FM; t++)
                af[kh][t] = *(const bf16x8*)&As[kh * TM * 32 + (wr * (TM / 2) + t * 16 + l16) * 32 + quad * 8];
#pragma unroll
        for (int kh = 0; kh < 2; kh++)
#pragma unroll
            for (int i = 0; i < FM; i++)
#pragma unroll
                for (int j = 0; j < FN; j++)
                    acc[i][j] = __builtin_amdgcn_mfma_f32_16x16x32_bf16(af[kh][i], bg[kh][j], acc[i][j], 0, 0, 0);
        __syncthreads();
    }

    // epilogue: C/D layout col=lane&15, row=quad*4+r (verified m89/m91)
#pragma unroll
    for (int i = 0; i < FM; i++) {
        int gm0 = m0 + wr * (TM / 2) + i * 16 + quad * 4;
#pragma unroll
        for (int j = 0; j < FN; j++) {
            int gn = n0 + wc * (TN / 2) + j * 16 + l16;
            if (gn >= N) continue;
            float bn = (biasMode == 1) ? bias[gn] : 0.0f;
            if (OUT_BF16 && vTout != nullptr && gn >= 2048) {
                // V columns -> vT[d][l]: r maps to contiguous l -> ushort4 store
                ushort4 o;
                o.x = f2bf(acc[i][j][0] * alpha + bn);
                o.y = f2bf(acc[i][j][1] * alpha + bn);
                o.z = f2bf(acc[i][j][2] * alpha + bn);
                o.w = f2bf(acc[i][j][3] * alpha + bn);
                *(ushort4*)&vTout[(long)(gn - 2048) * 512 + gm0] = o;
                continue;
            }
#pragma unroll
            for (int r = 0; r < 4; r++) {
                int gm = gm0 + r;
                if (gm >= M) continue;
                float v = acc[i][j][r] * alpha + bn;
                long idx = (long)gm * ldc + gn;
                if (OUT_BF16) ((u16*)Cm)[idx] = f2bf(v);
                else ((float*)Cm)[idx] = v;
            }
        }
    }
}

// ---------------- fused attention: scores+softmax+PV for one (head, 32-q-row) block ---
__global__ __launch_bounds__(128) void k_attn(
    const u16* __restrict__ qkv, const u16* __restrict__ vT, u16* __restrict__ Ob)
{
    __shared__ u16 Ks[2][4096];   // plane layout: idx(key,d) = (d>>5)*2048 + key*32 + (d&31)
    __shared__ u16 Vs[2][4096];   // idx(d,key)   = (key>>5)*2048 + d*32 + (key&31)
    __shared__ u16 Pl[32 * 72];   // [q_local][72]; 144B rows -> 16B-aligned
    int qb = blockIdx.x, h = blockIdx.y;
    int tid = threadIdx.x;
    int w = tid >> 6, lane = tid & 63;
    int quad = lane >> 4, l16 = lane & 15;

    int qrow = qb * 32 + w * 16 + l16;
    bf16x8 aq[2];
#pragma unroll
    for (int c = 0; c < 2; c++)
        aq[c] = *(const bf16x8*)&qkv[(long)qrow * 3072 + h * 64 + c * 32 + quad * 8];

    f32x4 acc_o[4];
#pragma unroll
    for (int j = 0; j < 4; j++) acc_o[j] = {0.f, 0.f, 0.f, 0.f};
    float mrow[4], lrow[4];
#pragma unroll
    for (int r = 0; r < 4; r++) { mrow[r] = -1e30f; lrow[r] = 0.f; }

    {
        int kt = 0;
#pragma unroll
        for (int rr = 0; rr < 4; rr++) {
            int c = rr * 2 + w;
            int loc = (c & 3) * 16 + (lane >> 2);
            int off8 = ((c >> 2) << 5) + (lane & 3) * 8;
            ASYNC_CP16(&qkv[(long)(kt * 64 + loc) * 3072 + 1024 + h * 64 + off8], &Ks[0][c * 512]);
            ASYNC_CP16(&vT[(long)(h * 64 + loc) * 512 + kt * 64 + off8], &Vs[0][c * 512]);
        }
    }
    __syncthreads();

    for (int kt = 0; kt < 8; kt++) {
        int buf = kt & 1;
        if (kt < 7) {
            int nb = buf ^ 1, ktn = kt + 1;
#pragma unroll
            for (int rr = 0; rr < 4; rr++) {
                int c = rr * 2 + w;
                int loc = (c & 3) * 16 + (lane >> 2);
                int off8 = ((c >> 2) << 5) + (lane & 3) * 8;
                ASYNC_CP16(&qkv[(long)(ktn * 64 + loc) * 3072 + 1024 + h * 64 + off8], &Ks[nb][c * 512]);
                ASYNC_CP16(&vT[(long)(h * 64 + loc) * 512 + ktn * 64 + off8], &Vs[nb][c * 512]);
            }
        }
        f32x4 s[4];
#pragma unroll
        for (int ss = 0; ss < 4; ss++) {
            s[ss] = {0.f, 0.f, 0.f, 0.f};
#pragma unroll
            for (int c = 0; c < 2; c++) {
                bf16x8 bk = *(const bf16x8*)&Ks[buf][c * 2048 + (ss * 16 + l16) * 32 + quad * 8];
                s[ss] = __builtin_amdgcn_mfma_f32_16x16x32_bf16(aq[c], bk, s[ss], 0, 0, 0);
            }
        }
        float mt[4];
#pragma unroll
        for (int r = 0; r < 4; r++) {
#pragma unroll
            for (int ss = 0; ss < 4; ss++) s[ss][r] *= 0.125f;
            mt[r] = fmaxf(fmaxf(s[0][r], s[1][r]), fmaxf(s[2][r], s[3][r]));
        }
#pragma unroll
        for (int mask = 1; mask < 16; mask <<= 1)
#pragma unroll
            for (int r = 0; r < 4; r++) mt[r] = fmaxf(mt[r], __shfl_xor(mt[r], mask));
        float al[4], rsum[4];
#pragma unroll
        for (int r = 0; r < 4; r++) {
            float mn = fmaxf(mrow[r], mt[r]);
            al[r] = exp2f((mrow[r] - mn) * L2E);
            mrow[r] = mn;
            rsum[r] = 0.f;
#pragma unroll
            for (int ss = 0; ss < 4; ss++) {
                float p = exp2f((s[ss][r] - mn) * L2E);
                s[ss][r] = p;
                rsum[r] += p;
            }
        }
#pragma unroll
        for (int mask = 1; mask < 16; mask <<= 1)
#pragma unroll
            for (int r = 0; r < 4; r++) rsum[r] += __shfl_xor(rsum[r], mask);
#pragma unroll
        for (int r = 0; r < 4; r++) lrow[r] = lrow[r] * al[r] + rsum[r];
#pragma unroll
        for (int j = 0; j < 4; j++)
#pragma unroll
            for (int r = 0; r < 4; r++) acc_o[j][r] *= al[r];
#pragma unroll
        for (int ss = 0; ss < 4; ss++)
#pragma unroll
            for (int r = 0; r < 4; r++)
                Pl[(w * 16 + quad * 4 + r) * 72 + ss * 16 + l16] = f2bf(s[ss][r]);
#pragma unroll
        for (int kc = 0; kc < 2; kc++) {
            bf16x8 ap = *(const bf16x8*)&Pl[(w * 16 + l16) * 72 + kc * 32 + quad * 8];
#pragma unroll
            for (int j = 0; j < 4; j++) {
                bf16x8 bv = *(const bf16x8*)&Vs[buf][kc * 2048 + (j * 16 + l16) * 32 + quad * 8];
                acc_o[j] = __builtin_amdgcn_mfma_f32_16x16x32_bf16(ap, bv, acc_o[j], 0, 0, 0);
            }
        }
        __syncthreads();
    }

#pragma unroll
    for (int r = 0; r < 4; r++) {
        float inv = 1.0f / lrow[r];
        int gq = qb * 32 + w * 16 + quad * 4 + r;
#pragma unroll
        for (int j = 0; j < 4; j++)
            Ob[(long)gq * 1024 + h * 64 + j * 16 + l16] = f2bf(acc_o[j][r] * inv);
    }
}

// ---------------- xb = bf16(LN(xb + s) * g + beta), wave-per-row, no barrier -----------
__global__ __launch_bounds__(256) void k_add_ln(
    u16* __restrict__ xb, const u16* __restrict__ s, int sBroadcast,
    const float* __restrict__ g, const float* __restrict__ beta)
{
    int row = blockIdx.x * 4 + (threadIdx.x >> 6);   // b*512 + l
    int lane = threadIdx.x & 63;
    int srow = sBroadcast ? (row & 511) : row;
    u16* x = xb + (long)row * 1024;
    const u16* sp = s + (long)srow * 1024;
    int d0 = lane * 16;
    uint4 xa = *(const uint4*)&x[d0];
    uint4 xc = *(const uint4*)&x[d0 + 8];
    uint4 sa = *(const uint4*)&sp[d0];
    uint4 sc = *(const uint4*)&sp[d0 + 8];
    float v[16], t[8];
    unp8(xa, v); unp8(xc, v + 8);
    unp8(sa, t);
#pragma unroll
    for (int i = 0; i < 8; i++) v[i] += t[i];
    unp8(sc, t);
#pragma unroll
    for (int i = 0; i < 8; i++) v[8 + i] += t[i];
    float sum = 0.f, sq = 0.f;
#pragma unroll
    for (int i = 0; i < 16; i++) { sum += v[i]; sq += v[i] * v[i]; }
#pragma unroll
    for (int off = 32; off; off >>= 1) {
        sum += __shfl_xor(sum, off);
        sq += __shfl_xor(sq, off);
    }
    float mean = sum * (1.f / 1024.f);
    float var = sq * (1.f / 1024.f) - mean * mean;
    float rstd = rsqrtf(var + LN_EPS);
    float4 g0 = *(const float4*)&g[d0],      g1 = *(const float4*)&g[d0 + 4];
    float4 g2 = *(const float4*)&g[d0 + 8],  g3 = *(const float4*)&g[d0 + 12];
    float4 b0 = *(const float4*)&beta[d0],     b1 = *(const float4*)&beta[d0 + 4];
    float4 b2 = *(const float4*)&beta[d0 + 8], b3 = *(const float4*)&beta[d0 + 12];
    float gg[16] = {g0.x,g0.y,g0.z,g0.w, g1.x,g1.y,g1.z,g1.w, g2.x,g2.y,g2.z,g2.w, g3.x,g3.y,g3.z,g3.w};
    float bb[16] = {b0.x,b0.y,b0.z,b0.w, b1.x,b1.y,b1.z,b1.w, b2.x,b2.y,b2.z,b2.w, b3.x,b3.y,b3.z,b3.w};
    float y[16];
#pragma unroll
    for (int i = 0; i < 16; i++) y[i] = (v[i] - mean) * rstd * gg[i] + bb[i];
    uint4 oa, oc;
    oa.x = pk2(y[0], y[1]);  oa.y = pk2(y[2], y[3]);
    oa.z = pk2(y[4], y[5]);  oa.w = pk2(y[6], y[7]);
    oc.x = pk2(y[8], y[9]);  oc.y = pk2(y[10], y[11]);
    oc.z = pk2(y[12], y[13]); oc.w = pk2(y[14], y[15]);
    *(uint4*)&x[d0] = oa;
    *(uint4*)&x[d0 + 8] = oc;
}

// ---------------- fused pool+head: out[b][c] = (mean_l x[b][l])·wf[:,c] + bf[c] -----
__global__ __launch_bounds__(256) void k_pool_head(
    const u16* __restrict__ xb, const float* __restrict__ wf,
    const float* __restrict__ bfin, float* __restrict__ out)
{
    int b = blockIdx.x;
    int tid = threadIdx.x;
    __shared__ float pl[1024];
    int d0 = tid * 4;
    const u16* x = xb + (long)b * 512 * 1024;
    float s0 = 0.f, s1 = 0.f, s2 = 0.f, s3 = 0.f;
    for (int l = 0; l < 512; l++) {
        ushort4 v = *(const ushort4*)&x[(long)l * 1024 + d0];
        s0 += bf2f(v.x); s1 += bf2f(v.y); s2 += bf2f(v.z); s3 += bf2f(v.w);
    }
    pl[d0] = s0 * (1.f / 512.f);
    pl[d0 + 1] = s1 * (1.f / 512.f);
    pl[d0 + 2] = s2 * (1.f / 512.f);
    pl[d0 + 3] = s3 * (1.f / 512.f);
    __syncthreads();
    __shared__ float red[4];
    for (int c = 0; c < 10; c++) {
        float t = 0.f;
        for (int d = tid; d < 1024; d += 256) t += pl[d] * wf[(long)d * 10 + c];
        for (int off = 32; off; off >>= 1) t += __shfl_down(t, off);
        if ((tid & 63) == 0) red[tid >> 6] = t;
        __syncthreads();
        if (tid == 0) out[b * 10 + c] = red[0] + red[1] + red[2] + red[3] + bfin[c];
        __syncthreads();
    }
}

// ---------------- host side ----------------
template <int TM, int TN>
static void gemm(bool outBf16, const u16* A, long lda,
                 const u16* B, long ldb,
                 void* C, long ldc,
                 int M, int N, int K, const float* bias, int biasMode, float alpha,
                 hipStream_t st, u16* vTout = nullptr)
{
    dim3 g((M + TM - 1) / TM, (N + TN - 1) / TN);   // m fastest -> B-panel L2 reuse
    if (outBf16)
        k_gemm_nt<TM, TN, true><<<g, 256, 0, st>>>(A, lda, B, ldb, C, ldc, M, N, K, bias, biasMode, alpha, vTout);
    else
        k_gemm_nt<TM, TN, false><<<g, 256, 0, st>>>(A, lda, B, ldb, C, ldc, M, N, K, bias, biasMode, alpha, vTout);
}

extern "C" void kernel_launch(void* const* d_in, const int* in_sizes, int n_in,
                              void* d_out, int out_size, void* d_ws, size_t ws_size,
                              hipStream_t stream)
{
    const int* ids   = (const int*)d_in[0];
    const float* emb = (const float*)d_in[1];
    const float* pe  = (const float*)d_in[2];
    const float* wq  = (const float*)d_in[3];
    const float* bq  = (const float*)d_in[4];
    const float* wk  = (const float*)d_in[5];
    const float* bk  = (const float*)d_in[6];
    const float* wv  = (const float*)d_in[7];
    const float* bv  = (const float*)d_in[8];
    const float* wo  = (const float*)d_in[9];
    const float* bo  = (const float*)d_in[10];
    const float* w1  = (const float*)d_in[11];
    const float* b1  = (const float*)d_in[12];
    const float* w2  = (const float*)d_in[13];
    const float* b2  = (const float*)d_in[14];
    const float* g1  = (const float*)d_in[15];
    const float* be1 = (const float*)d_in[16];
    const float* g2  = (const float*)d_in[17];
    const float* be2 = (const float*)d_in[18];
    const float* wf  = (const float*)d_in[19];
    const float* bfi = (const float*)d_in[20];
    float* out = (float*)d_out;

    char* base = (char*)d_ws;
    size_t off = 0;
    auto alloc = [&](size_t bytes) {
        char* p = base + off;
        off = (off + bytes + 255) & ~(size_t)255;
        return p;
    };
    u16*   xb    = (u16*)  alloc(16UL * 512 * 1024 * 2);   // bf16 residual stream [B,L,D]
    u16*   wqkvT = (u16*)  alloc(3072UL * 1024 * 2);       // [3072,1024] = wqT;wkT;wvT
    u16*   woT   = (u16*)  alloc(1024UL * 1024 * 2);
    u16*   w1T   = (u16*)  alloc(4096UL * 1024 * 2);       // [F,D]
    u16*   w2T   = (u16*)  alloc(1024UL * 4096 * 2);       // [D,F]
    float* qkvb  = (float*)alloc(3072UL * 4);              // concat(bq,bk,bv)
    u16*   qkv   = (u16*)  alloc(512UL * 3072 * 2);        // [L, 3*D]; v-part unused (goes to vT)
    u16*   vT    = (u16*)  alloc(1024UL * 512 * 2);        // v transposed [D,L]
    u16*   Ob    = (u16*)  alloc(512UL * 1024 * 2);        // attn context bf16 [L,D]
    u16*   src2  = (u16*)  alloc(512UL * 1024 * 2);        // bf16
    u16*   Hb    = (u16*)  alloc(8192UL * 4096 * 2);       // FFN hidden bf16
    u16*   ffb   = (u16*)  alloc(8192UL * 1024 * 2);       // bf16

    k_prep<<<12300, 256, 0, stream>>>(wq, wk, wv, wo, w1, w2, bq, bk, bv, qkvb,
                                      wqkvT, woT, w1T, w2T);
    k_embed<<<8192, 256, 0, stream>>>(ids, emb, pe, xb);

    for (int layer = 0; layer < 6; layer++) {
        // fused q|k|v for batch 0: [512,3072]; V cols written transposed into vT
        gemm<64, 64>(true, xb, 1024, wqkvT, 1024, qkv, 3072, 512, 3072, 1024, qkvb, 1, 1.f, stream, vT);
        // fused scores+softmax+PV
        k_attn<<<dim3(16, 16), 128, 0, stream>>>(qkv, vT, Ob);
        // src2 = O . wo + bo
        gemm<64, 64>(true, Ob, 1024, woT, 1024, src2, 1024, 512, 1024, 1024, bo, 1, 1.f, stream);
        k_add_ln<<<2048, 256, 0, stream>>>(xb, src2, 1, g1, be1);
        // FFN (128-tiles)
        gemm<128, 128>(true, xb, 1024, w1T, 1024, Hb, 4096, 8192, 4096, 1024, b1, 1, 1.f, stream);
        gemm<128, 128>(true, Hb, 4096, w2T, 4096, ffb, 1024, 8192, 1024, 4096, b2, 1, 1.f, stream);
        k_add_ln<<<2048, 256, 0, stream>>>(xb, ffb, 0, g2, be2);
    }

    k_pool_head<<<16, 256, 0, stream>>>(xb, wf, bfi, out);
}

// Round 7
// 1857.714 us; speedup vs baseline: 1.4755x; 1.4755x over previous
//
#include <hip/hip_runtime.h>

typedef unsigned short u16;
typedef unsigned int u32;
typedef __bf16 bf16x8 __attribute__((ext_vector_type(8)));
typedef float f32x4 __attribute__((ext_vector_type(4)));

#define LN_EPS 1e-5f
#define L2E 1.44269504f

__device__ __forceinline__ u16 f2bf(float f) {
    u32 u = __float_as_uint(f);
    u += 0x7fffu + ((u >> 16) & 1u);
    return (u16)(u >> 16);
}
__device__ __forceinline__ float bf2f(u32 v) {
    return __uint_as_float(v << 16);
}
__device__ __forceinline__ void unp8(uint4 u, float* v) {
    v[0] = bf2f(u.x & 0xffff); v[1] = bf2f(u.x >> 16);
    v[2] = bf2f(u.y & 0xffff); v[3] = bf2f(u.y >> 16);
    v[4] = bf2f(u.z & 0xffff); v[5] = bf2f(u.z >> 16);
    v[6] = bf2f(u.w & 0xffff); v[7] = bf2f(u.w >> 16);
}
__device__ __forceinline__ u32 pk2(float a, float b) {
    return (u32)f2bf(a) | ((u32)f2bf(b) << 16);
}

// async global->LDS, 16B per lane; lds base must be wave-uniform (HW: base + lane*16)
#define ASYNC_CP16(g, l)                                                      \
    __builtin_amdgcn_global_load_lds(                                         \
        (const __attribute__((address_space(1))) u32*)(g),                    \
        (__attribute__((address_space(3))) u32*)(l), 16, 0, 0)

// ---------------- one-shot prep: all weight transposes (f32->bf16) + bias concat ----
__global__ __launch_bounds__(256) void k_prep(
    const float* __restrict__ wq, const float* __restrict__ wk,
    const float* __restrict__ wv, const float* __restrict__ wo,
    const float* __restrict__ w1, const float* __restrict__ w2,
    const float* __restrict__ bq, const float* __restrict__ bk,
    const float* __restrict__ bv, float* __restrict__ qkvb,
    u16* __restrict__ wqkvT, u16* __restrict__ woT,
    u16* __restrict__ w1T, u16* __restrict__ w2T)
{
    int b = blockIdx.x;
    if (b >= 12288) {
        int i = (b - 12288) * 256 + threadIdx.x;
        qkvb[i] = (i < 1024) ? bq[i] : (i < 2048 ? bk[i - 1024] : bv[i - 2048]);
        return;
    }
    const float* in; u16* out; int C; long ldo; int gx; int l;
    if (b < 4096) {
        int j = b >> 10; l = b & 1023;
        in = (j == 0) ? wq : (j == 1) ? wk : (j == 2) ? wv : wo;
        out = (j == 3) ? woT : wqkvT + (long)j * 1024 * 1024;
        C = 1024; ldo = 1024; gx = 32;
    } else if (b < 8192) {
        l = b - 4096; in = w1; out = w1T; C = 4096; ldo = 1024; gx = 128;
    } else {
        l = b - 8192; in = w2; out = w2T; C = 1024; ldo = 4096; gx = 32;
    }
    int bx = l % gx, by = l / gx;
    __shared__ float tile[32][33];
    int c0 = bx * 32, r0 = by * 32;
    int tx = threadIdx.x & 31, ty = threadIdx.x >> 5;
#pragma unroll
    for (int i = 0; i < 4; i++)
        tile[ty + 8 * i][tx] = in[(long)(r0 + ty + 8 * i) * C + c0 + tx];
    __syncthreads();
#pragma unroll
    for (int i = 0; i < 4; i++)
        out[(long)(c0 + ty + 8 * i) * ldo + r0 + tx] = f2bf(tile[tx][ty + 8 * i]);
}

// ---------------- embedding: xb = bf16(emb[id]*32 + pe) ----------------
__global__ __launch_bounds__(256) void k_embed(
    const int* __restrict__ ids, const float* __restrict__ emb,
    const float* __restrict__ pe, u16* __restrict__ xb)
{
    int row = blockIdx.x;          // b*512 + l
    int l = row & 511;
    long id = (long)ids[row];
    const float* e = emb + id * 1024;
    const float* p = pe + (long)l * 1024;
    u16* xbo = xb + (long)row * 1024;
    int d0 = threadIdx.x * 4;
    float4 ev = *(const float4*)&e[d0];
    float4 pv = *(const float4*)&p[d0];
    ushort4 o;
    o.x = f2bf(ev.x * 32.0f + pv.x);
    o.y = f2bf(ev.y * 32.0f + pv.y);
    o.z = f2bf(ev.z * 32.0f + pv.z);
    o.w = f2bf(ev.w * 32.0f + pv.w);
    *(ushort4*)&xbo[d0] = o;
}

// ---------------- bf16 MFMA GEMM, NT form: C[m][n] = alpha*sum_k A[m][k]*B[n][k] + bias ----
// Round-5 proven structure: BOTH operands staged via global_load_lds (shared across waves),
// BK=64 (2 conflict-free K-planes), 4 waves (2x2). bias[n] only.
// If VT_EPI: bf16 cols gn>=2048 written transposed to vTout[gn-2048][gm] (ld 512).
template <int TM, int TN, bool VT_EPI>
__global__ __launch_bounds__(256) void k_gemm_nt(
    const u16* __restrict__ A, long lda,
    const u16* __restrict__ B, long ldb,
    u16* __restrict__ Cm, long ldc,
    int M, int N, int K,
    const float* __restrict__ bias,
    u16* __restrict__ vTout)
{
    constexpr int FM = TM / 32;     // m-frags per wave
    constexpr int FN = TN / 32;     // n-frags per wave
    constexpr int CPA = TM / 64;    // A chunks per wave per K-plane
    constexpr int CPB = TN / 64;
    __shared__ u16 As[2 * TM * 32];
    __shared__ u16 Bs[2 * TN * 32];
    int m0 = blockIdx.y * TM, n0 = blockIdx.x * TN;
    int tid = threadIdx.x;
    int lane = tid & 63, wid = tid >> 6;
    int wr = wid >> 1, wc = wid & 1;
    int quad = lane >> 4, l16 = lane & 15;

    f32x4 acc[FM][FN];
#pragma unroll
    for (int i = 0; i < FM; i++)
#pragma unroll
        for (int j = 0; j < FN; j++) acc[i][j] = {0.f, 0.f, 0.f, 0.f};

    // staging: chunk = 16 rows x 32 k (1KB); lane l -> row c*16 + l/4, k-seg (l%4)*8
    int seg = (lane & 3) * 8;
    const u16* pA[CPA]; u16* lA[2][CPA];
    const u16* pB[CPB]; u16* lB[2][CPB];
#pragma unroll
    for (int i = 0; i < CPA; i++) {
        int c = wid * CPA + i;
        int gm = min(m0 + c * 16 + (lane >> 2), M - 1);
        pA[i] = A + (long)gm * lda + seg;
        lA[0][i] = &As[c * 512];
        lA[1][i] = &As[TM * 32 + c * 512];
    }
#pragma unroll
    for (int i = 0; i < CPB; i++) {
        int c = wid * CPB + i;
        int gn = min(n0 + c * 16 + (lane >> 2), N - 1);
        pB[i] = B + (long)gn * ldb + seg;
        lB[0][i] = &Bs[c * 512];
        lB[1][i] = &Bs[TN * 32 + c * 512];
    }

    for (int kb = 0; kb < K; kb += 64) {
#pragma unroll
        for (int kh = 0; kh < 2; kh++) {
#pragma unroll
            for (int i = 0; i < CPA; i++) ASYNC_CP16(pA[i] + kb + kh * 32, lA[kh][i]);
#pragma unroll
            for (int i = 0; i < CPB; i++) ASYNC_CP16(pB[i] + kb + kh * 32, lB[kh][i]);
        }
        __syncthreads();
        bf16x8 af[2][FM], bg[2][FN];
#pragma unroll
        for (int kh = 0; kh < 2; kh++)
#pragma unroll
            for (int t = 0; t < FM; t++)
                af[kh][t] = *(const bf16x8*)&As[kh * TM * 32 + (wr * (TM / 2) + t * 16 + l16) * 32 + quad * 8];
#pragma unroll
        for (int kh = 0; kh < 2; kh++)
#pragma unroll
            for (int t = 0; t < FN; t++)
                bg[kh][t] = *(const bf16x8*)&Bs[kh * TN * 32 + (wc * (TN / 2) + t * 16 + l16) * 32 + quad * 8];
#pragma unroll
        for (int kh = 0; kh < 2; kh++)
#pragma unroll
            for (int i = 0; i < FM; i++)
#pragma unroll
                for (int j = 0; j < FN; j++)
                    acc[i][j] = __builtin_amdgcn_mfma_f32_16x16x32_bf16(af[kh][i], bg[kh][j], acc[i][j], 0, 0, 0);
        __syncthreads();
    }

    // epilogue: C/D layout col=lane&15, row=quad*4+r (verified m89/m91)
#pragma unroll
    for (int i = 0; i < FM; i++) {
        int gm0 = m0 + wr * (TM / 2) + i * 16 + quad * 4;
#pragma unroll
        for (int j = 0; j < FN; j++) {
            int gn = n0 + wc * (TN / 2) + j * 16 + l16;
            if (gn >= N) continue;
            float bn = bias[gn];
            if (VT_EPI && gn >= 2048) {
                // V columns -> vT[d][l]: r maps to contiguous l -> ushort4 store
                ushort4 o;
                o.x = f2bf(acc[i][j][0] + bn);
                o.y = f2bf(acc[i][j][1] + bn);
                o.z = f2bf(acc[i][j][2] + bn);
                o.w = f2bf(acc[i][j][3] + bn);
                *(ushort4*)&vTout[(long)(gn - 2048) * 512 + gm0] = o;
                continue;
            }
#pragma unroll
            for (int r = 0; r < 4; r++) {
                int gm = gm0 + r;
                if (gm >= M) continue;
                Cm[(long)gm * ldc + gn] = f2bf(acc[i][j][r] + bn);
            }
        }
    }
}

// ---------------- fused attention: scores+softmax+PV for one (head, 32-q-row) block ---
__global__ __launch_bounds__(128) void k_attn(
    const u16* __restrict__ qkv, const u16* __restrict__ vT, u16* __restrict__ Ob)
{
    __shared__ u16 Ks[2][4096];   // plane layout: idx(key,d) = (d>>5)*2048 + key*32 + (d&31)
    __shared__ u16 Vs[2][4096];   // idx(d,key)   = (key>>5)*2048 + d*32 + (key&31)
    __shared__ u16 Pl[32 * 72];   // [q_local][72]; 144B rows -> 16B-aligned
    int qb = blockIdx.x, h = blockIdx.y;
    int tid = threadIdx.x;
    int w = tid >> 6, lane = tid & 63;
    int quad = lane >> 4, l16 = lane & 15;

    int qrow = qb * 32 + w * 16 + l16;
    bf16x8 aq[2];
#pragma unroll
    for (int c = 0; c < 2; c++)
        aq[c] = *(const bf16x8*)&qkv[(long)qrow * 3072 + h * 64 + c * 32 + quad * 8];

    f32x4 acc_o[4];
#pragma unroll
    for (int j = 0; j < 4; j++) acc_o[j] = {0.f, 0.f, 0.f, 0.f};
    float mrow[4], lrow[4];
#pragma unroll
    for (int r = 0; r < 4; r++) { mrow[r] = -1e30f; lrow[r] = 0.f; }

    {
        int kt = 0;
#pragma unroll
        for (int rr = 0; rr < 4; rr++) {
            int c = rr * 2 + w;
            int loc = (c & 3) * 16 + (lane >> 2);
            int off8 = ((c >> 2) << 5) + (lane & 3) * 8;
            ASYNC_CP16(&qkv[(long)(kt * 64 + loc) * 3072 + 1024 + h * 64 + off8], &Ks[0][c * 512]);
            ASYNC_CP16(&vT[(long)(h * 64 + loc) * 512 + kt * 64 + off8], &Vs[0][c * 512]);
        }
    }
    __syncthreads();

    for (int kt = 0; kt < 8; kt++) {
        int buf = kt & 1;
        if (kt < 7) {
            int nb = buf ^ 1, ktn = kt + 1;
#pragma unroll
            for (int rr = 0; rr < 4; rr++) {
                int c = rr * 2 + w;
                int loc = (c & 3) * 16 + (lane >> 2);
                int off8 = ((c >> 2) << 5) + (lane & 3) * 8;
                ASYNC_CP16(&qkv[(long)(ktn * 64 + loc) * 3072 + 1024 + h * 64 + off8], &Ks[nb][c * 512]);
                ASYNC_CP16(&vT[(long)(h * 64 + loc) * 512 + ktn * 64 + off8], &Vs[nb][c * 512]);
            }
        }
        f32x4 s[4];
#pragma unroll
        for (int ss = 0; ss < 4; ss++) {
            s[ss] = {0.f, 0.f, 0.f, 0.f};
#pragma unroll
            for (int c = 0; c < 2; c++) {
                bf16x8 bk = *(const bf16x8*)&Ks[buf][c * 2048 + (ss * 16 + l16) * 32 + quad * 8];
                s[ss] = __builtin_amdgcn_mfma_f32_16x16x32_bf16(aq[c], bk, s[ss], 0, 0, 0);
            }
        }
        float mt[4];
#pragma unroll
        for (int r = 0; r < 4; r++) {
#pragma unroll
            for (int ss = 0; ss < 4; ss++) s[ss][r] *= 0.125f;
            mt[r] = fmaxf(fmaxf(s[0][r], s[1][r]), fmaxf(s[2][r], s[3][r]));
        }
#pragma unroll
        for (int mask = 1; mask < 16; mask <<= 1)
#pragma unroll
            for (int r = 0; r < 4; r++) mt[r] = fmaxf(mt[r], __shfl_xor(mt[r], mask));
        float al[4], rsum[4];
#pragma unroll
        for (int r = 0; r < 4; r++) {
            float mn = fmaxf(mrow[r], mt[r]);
            al[r] = exp2f((mrow[r] - mn) * L2E);
            mrow[r] = mn;
            rsum[r] = 0.f;
#pragma unroll
            for (int ss = 0; ss < 4; ss++) {
                float p = exp2f((s[ss][r] - mn) * L2E);
                s[ss][r] = p;
                rsum[r] += p;
            }
        }
#pragma unroll
        for (int mask = 1; mask < 16; mask <<= 1)
#pragma unroll
            for (int r = 0; r < 4; r++) rsum[r] += __shfl_xor(rsum[r], mask);
#pragma unroll
        for (int r = 0; r < 4; r++) lrow[r] = lrow[r] * al[r] + rsum[r];
#pragma unroll
        for (int j = 0; j < 4; j++)
#pragma unroll
            for (int r = 0; r < 4; r++) acc_o[j][r] *= al[r];
#pragma unroll
        for (int ss = 0; ss < 4; ss++)
#pragma unroll
            for (int r = 0; r < 4; r++)
                Pl[(w * 16 + quad * 4 + r) * 72 + ss * 16 + l16] = f2bf(s[ss][r]);
#pragma unroll
        for (int kc = 0; kc < 2; kc++) {
            bf16x8 ap = *(const bf16x8*)&Pl[(w * 16 + l16) * 72 + kc * 32 + quad * 8];
#pragma unroll
            for (int j = 0; j < 4; j++) {
                bf16x8 bv = *(const bf16x8*)&Vs[buf][kc * 2048 + (j * 16 + l16) * 32 + quad * 8];
                acc_o[j] = __builtin_amdgcn_mfma_f32_16x16x32_bf16(ap, bv, acc_o[j], 0, 0, 0);
            }
        }
        __syncthreads();
    }

#pragma unroll
    for (int r = 0; r < 4; r++) {
        float inv = 1.0f / lrow[r];
        int gq = qb * 32 + w * 16 + quad * 4 + r;
#pragma unroll
        for (int j = 0; j < 4; j++)
            Ob[(long)gq * 1024 + h * 64 + j * 16 + l16] = f2bf(acc_o[j][r] * inv);
    }
}

// ---------------- xb = bf16(LN(xb + s) * g + beta), wave-per-row, no barrier -----------
__global__ __launch_bounds__(256) void k_add_ln(
    u16* __restrict__ xb, const u16* __restrict__ s, int sBroadcast,
    const float* __restrict__ g, const float* __restrict__ beta)
{
    int row = blockIdx.x * 4 + (threadIdx.x >> 6);   // b*512 + l
    int lane = threadIdx.x & 63;
    int srow = sBroadcast ? (row & 511) : row;
    u16* x = xb + (long)row * 1024;
    const u16* sp = s + (long)srow * 1024;
    int d0 = lane * 16;
    uint4 xa = *(const uint4*)&x[d0];
    uint4 xc = *(const uint4*)&x[d0 + 8];
    uint4 sa = *(const uint4*)&sp[d0];
    uint4 sc = *(const uint4*)&sp[d0 + 8];
    float v[16], t[8];
    unp8(xa, v); unp8(xc, v + 8);
    unp8(sa, t);
#pragma unroll
    for (int i = 0; i < 8; i++) v[i] += t[i];
    unp8(sc, t);
#pragma unroll
    for (int i = 0; i < 8; i++) v[8 + i] += t[i];
    float sum = 0.f, sq = 0.f;
#pragma unroll
    for (int i = 0; i < 16; i++) { sum += v[i]; sq += v[i] * v[i]; }
#pragma unroll
    for (int off = 32; off; off >>= 1) {
        sum += __shfl_xor(sum, off);
        sq += __shfl_xor(sq, off);
    }
    float mean = sum * (1.f / 1024.f);
    float var = sq * (1.f / 1024.f) - mean * mean;
    float rstd = rsqrtf(var + LN_EPS);
    float4 g0 = *(const float4*)&g[d0],      g1 = *(const float4*)&g[d0 + 4];
    float4 g2 = *(const float4*)&g[d0 + 8],  g3 = *(const float4*)&g[d0 + 12];
    float4 b0 = *(const float4*)&beta[d0],     b1 = *(const float4*)&beta[d0 + 4];
    float4 b2 = *(const float4*)&beta[d0 + 8], b3 = *(const float4*)&beta[d0 + 12];
    float gg[16] = {g0.x,g0.y,g0.z,g0.w, g1.x,g1.y,g1.z,g1.w, g2.x,g2.y,g2.z,g2.w, g3.x,g3.y,g3.z,g3.w};
    float bb[16] = {b0.x,b0.y,b0.z,b0.w, b1.x,b1.y,b1.z,b1.w, b2.x,b2.y,b2.z,b2.w, b3.x,b3.y,b3.z,b3.w};
    float y[16];
#pragma unroll
    for (int i = 0; i < 16; i++) y[i] = (v[i] - mean) * rstd * gg[i] + bb[i];
    uint4 oa, oc;
    oa.x = pk2(y[0], y[1]);  oa.y = pk2(y[2], y[3]);
    oa.z = pk2(y[4], y[5]);  oa.w = pk2(y[6], y[7]);
    oc.x = pk2(y[8], y[9]);  oc.y = pk2(y[10], y[11]);
    oc.z = pk2(y[12], y[13]); oc.w = pk2(y[14], y[15]);
    *(uint4*)&x[d0] = oa;
    *(uint4*)&x[d0 + 8] = oc;
}

// ---------------- fused pool+head: out[b][c] = (mean_l x[b][l])·wf[:,c] + bf[c] -----
__global__ __launch_bounds__(256) void k_pool_head(
    const u16* __restrict__ xb, const float* __restrict__ wf,
    const float* __restrict__ bfin, float* __restrict__ out)
{
    int b = blockIdx.x;
    int tid = threadIdx.x;
    __shared__ float pl[1024];
    int d0 = tid * 4;
    const u16* x = xb + (long)b * 512 * 1024;
    float s0 = 0.f, s1 = 0.f, s2 = 0.f, s3 = 0.f;
    for (int l = 0; l < 512; l++) {
        ushort4 v = *(const ushort4*)&x[(long)l * 1024 + d0];
        s0 += bf2f(v.x); s1 += bf2f(v.y); s2 += bf2f(v.z); s3 += bf2f(v.w);
    }
    pl[d0] = s0 * (1.f / 512.f);
    pl[d0 + 1] = s1 * (1.f / 512.f);
    pl[d0 + 2] = s2 * (1.f / 512.f);
    pl[d0 + 3] = s3 * (1.f / 512.f);
    __syncthreads();
    __shared__ float red[4];
    for (int c = 0; c < 10; c++) {
        float t = 0.f;
        for (int d = tid; d < 1024; d += 256) t += pl[d] * wf[(long)d * 10 + c];
        for (int off = 32; off; off >>= 1) t += __shfl_down(t, off);
        if ((tid & 63) == 0) red[tid >> 6] = t;
        __syncthreads();
        if (tid == 0) out[b * 10 + c] = red[0] + red[1] + red[2] + red[3] + bfin[c];
        __syncthreads();
    }
}

// ---------------- host side ----------------
template <int TM, int TN, bool VT_EPI>
static void gemm(const u16* A, long lda, const u16* B, long ldb,
                 u16* C, long ldc,
                 int M, int N, int K, const float* bias,
                 hipStream_t st, u16* vTout = nullptr)
{
    dim3 g((N + TN - 1) / TN, (M + TM - 1) / TM);
    k_gemm_nt<TM, TN, VT_EPI><<<g, 256, 0, st>>>(A, lda, B, ldb, C, ldc, M, N, K, bias, vTout);
}

extern "C" void kernel_launch(void* const* d_in, const int* in_sizes, int n_in,
                              void* d_out, int out_size, void* d_ws, size_t ws_size,
                              hipStream_t stream)
{
    const int* ids   = (const int*)d_in[0];
    const float* emb = (const float*)d_in[1];
    const float* pe  = (const float*)d_in[2];
    const float* wq  = (const float*)d_in[3];
    const float* bq  = (const float*)d_in[4];
    const float* wk  = (const float*)d_in[5];
    const float* bk  = (const float*)d_in[6];
    const float* wv  = (const float*)d_in[7];
    const float* bv  = (const float*)d_in[8];
    const float* wo  = (const float*)d_in[9];
    const float* bo  = (const float*)d_in[10];
    const float* w1  = (const float*)d_in[11];
    const float* b1  = (const float*)d_in[12];
    const float* w2  = (const float*)d_in[13];
    const float* b2  = (const float*)d_in[14];
    const float* g1  = (const float*)d_in[15];
    const float* be1 = (const float*)d_in[16];
    const float* g2  = (const float*)d_in[17];
    const float* be2 = (const float*)d_in[18];
    const float* wf  = (const float*)d_in[19];
    const float* bfi = (const float*)d_in[20];
    float* out = (float*)d_out;

    char* base = (char*)d_ws;
    size_t off = 0;
    auto alloc = [&](size_t bytes) {
        char* p = base + off;
        off = (off + bytes + 255) & ~(size_t)255;
        return p;
    };
    u16*   xb    = (u16*)  alloc(16UL * 512 * 1024 * 2);   // bf16 residual stream [B,L,D]
    u16*   wqkvT = (u16*)  alloc(3072UL * 1024 * 2);       // [3072,1024] = wqT;wkT;wvT
    u16*   woT   = (u16*)  alloc(1024UL * 1024 * 2);
    u16*   w1T   = (u16*)  alloc(4096UL * 1024 * 2);       // [F,D]
    u16*   w2T   = (u16*)  alloc(1024UL * 4096 * 2);       // [D,F]
    float* qkvb  = (float*)alloc(3072UL * 4);              // concat(bq,bk,bv)
    u16*   qkv   = (u16*)  alloc(512UL * 3072 * 2);        // [L, 3*D]; v-part unused (goes to vT)
    u16*   vT    = (u16*)  alloc(1024UL * 512 * 2);        // v transposed [D,L]
    u16*   Ob    = (u16*)  alloc(512UL * 1024 * 2);        // attn context bf16 [L,D]
    u16*   src2  = (u16*)  alloc(512UL * 1024 * 2);        // bf16
    u16*   Hb    = (u16*)  alloc(8192UL * 4096 * 2);       // FFN hidden bf16
    u16*   ffb   = (u16*)  alloc(8192UL * 1024 * 2);       // bf16

    k_prep<<<12300, 256, 0, stream>>>(wq, wk, wv, wo, w1, w2, bq, bk, bv, qkvb,
                                      wqkvT, woT, w1T, w2T);
    k_embed<<<8192, 256, 0, stream>>>(ids, emb, pe, xb);

    for (int layer = 0; layer < 6; layer++) {
        // fused q|k|v for batch 0: [512,3072]; V cols written transposed into vT
        gemm<64, 64, true>(xb, 1024, wqkvT, 1024, qkv, 3072, 512, 3072, 1024, qkvb, stream, vT);
        // fused scores+softmax+PV
        k_attn<<<dim3(16, 16), 128, 0, stream>>>(qkv, vT, Ob);
        // src2 = O . wo + bo
        gemm<64, 64, false>(Ob, 1024, woT, 1024, src2, 1024, 512, 1024, 1024, bo, stream);
        k_add_ln<<<2048, 256, 0, stream>>>(xb, src2, 1, g1, be1);
        // FFN (128-tiles)
        gemm<128, 128, false>(xb, 1024, w1T, 1024, Hb, 4096, 8192, 4096, 1024, b1, stream);
        gemm<128, 128, false>(Hb, 4096, w2T, 4096, ffb, 1024, 8192, 1024, 4096, b2, stream);
        k_add_ln<<<2048, 256, 0, stream>>>(xb, ffb, 0, g2, be2);
    }

    k_pool_head<<<16, 256, 0, stream>>>(xb, wf, bfi, out);
}